// Round 11
// baseline (1172.252 us; speedup 1.0000x reference)
//
#include <hip/hip_runtime.h>
#include <hip/hip_cooperative_groups.h>

namespace cg = cooperative_groups;

__device__ __forceinline__ float lrelu(float v) { return v > 0.0f ? v : 0.2f * v; }
__device__ __forceinline__ unsigned int bf16rne(float f) {
    unsigned int u = __float_as_uint(f);
    return (u + 0x7fffu + ((u >> 16) & 1u)) >> 16;
}
__device__ __forceinline__ unsigned int packbf(float a, float b) {
    return bf16rne(a) | (bf16rne(b) << 16);
}
__device__ __forceinline__ float bflo(unsigned int u) { return __uint_as_float(u << 16); }
__device__ __forceinline__ float bfhi(unsigned int u) { return __uint_as_float(u & 0xffff0000u); }

struct MegaP {
    const float* x; const int* ei; const int* batch;
    const float* W1; const float* attS1; const float* attD1;
    const float* bng1; const float* bnb1;
    const float* W2; const float* attS2; const float* attD2;
    const float* bng2; const float* bnb2;
    const float* d1W; const float* d1b; const float* gd1; const float* bd1;
    const float* d2W; const float* d2b; const float* gd2; const float* bd2;
    const float* fcW; const float* fcb;
    float* out;
    unsigned short* hbuf; unsigned short* outb;
    float* as_; float* ad_;
    float* zbase; int zcount;
    double* bnsumA; double* bnsumB;
    float* gsum; float* gcnt; int* bSize;
    int* rowPtr; int* sSrc; int* bOff; int* bCur;
    unsigned int* bucketBuf; float* gmean;
    int N; int E; int nB;
};

// ---- gemm phase body (shared by layer1 K=16 / layer2 K=128) is written inline ----

__global__ __launch_bounds__(256) void k_mega(MegaP P)
{
    __shared__ __align__(16) char smem[33792];
    cg::grid_group grid = cg::this_grid();
    const int t   = threadIdx.x;
    const int bid = blockIdx.x;
    const int g   = gridDim.x;
    const int N = P.N, E = P.E, nB = P.nB;
    const int cq = t & 31;
    const int nr = t >> 5;

    // ================= P0: zero region + gemm1 =================
    for (int i = bid * 256 + t; i < P.zcount; i += g * 256) P.zbase[i] = 0.f;
    {
        float* xs = (float*)smem;  // [64][16]
        const float4* W4 = (const float4*)P.W1;
        float4 atS = ((const float4*)P.attS1)[cq];
        float4 atD = ((const float4*)P.attD1)[cq];
        for (int n0 = bid * 64; n0 < N; n0 += g * 64) {
            int nrem = N - n0; if (nrem > 64) nrem = 64;
            for (int idx = t; idx < 64 * 4; idx += 256) {
                int n = idx >> 2, k4 = idx & 3;
                float4 v = make_float4(0.f, 0.f, 0.f, 0.f);
                if (n < nrem) v = ((const float4*)(P.x + (size_t)(n0 + n) * 16))[k4];
                *(float4*)(xs + n * 16 + k4 * 4) = v;
            }
            __syncthreads();
            float4 acc[8];
#pragma unroll
            for (int j = 0; j < 8; ++j) acc[j] = make_float4(0.f, 0.f, 0.f, 0.f);
#pragma unroll
            for (int k4 = 0; k4 < 4; ++k4) {
                float4 w0 = W4[(k4 * 4 + 0) * 32 + cq];
                float4 w1 = W4[(k4 * 4 + 1) * 32 + cq];
                float4 w2 = W4[(k4 * 4 + 2) * 32 + cq];
                float4 w3 = W4[(k4 * 4 + 3) * 32 + cq];
#pragma unroll
                for (int j = 0; j < 8; ++j) {
                    float4 xv = *(const float4*)(xs + (nr * 8 + j) * 16 + k4 * 4);
                    acc[j].x = fmaf(xv.x, w0.x, acc[j].x); acc[j].y = fmaf(xv.x, w0.y, acc[j].y);
                    acc[j].z = fmaf(xv.x, w0.z, acc[j].z); acc[j].w = fmaf(xv.x, w0.w, acc[j].w);
                    acc[j].x = fmaf(xv.y, w1.x, acc[j].x); acc[j].y = fmaf(xv.y, w1.y, acc[j].y);
                    acc[j].z = fmaf(xv.y, w1.z, acc[j].z); acc[j].w = fmaf(xv.y, w1.w, acc[j].w);
                    acc[j].x = fmaf(xv.z, w2.x, acc[j].x); acc[j].y = fmaf(xv.z, w2.y, acc[j].y);
                    acc[j].z = fmaf(xv.z, w2.z, acc[j].z); acc[j].w = fmaf(xv.z, w2.w, acc[j].w);
                    acc[j].x = fmaf(xv.w, w3.x, acc[j].x); acc[j].y = fmaf(xv.w, w3.y, acc[j].y);
                    acc[j].z = fmaf(xv.w, w3.z, acc[j].z); acc[j].w = fmaf(xv.w, w3.w, acc[j].w);
                }
            }
#pragma unroll
            for (int j = 0; j < 8; ++j) {
                int n = nr * 8 + j;
                bool ok = (n < nrem);
                if (ok) {
                    ((uint2*)(P.hbuf + (size_t)(n0 + n) * 128))[cq] =
                        make_uint2(packbf(acc[j].x, acc[j].y), packbf(acc[j].z, acc[j].w));
                }
                float ps = acc[j].x * atS.x + acc[j].y * atS.y + acc[j].z * atS.z + acc[j].w * atS.w;
                float pd = acc[j].x * atD.x + acc[j].y * atD.y + acc[j].z * atD.z + acc[j].w * atD.w;
                ps += __shfl_xor(ps, 1); pd += __shfl_xor(pd, 1);
                ps += __shfl_xor(ps, 2); pd += __shfl_xor(pd, 2);
                ps += __shfl_xor(ps, 4); pd += __shfl_xor(pd, 4);
                if (ok && (cq & 7) == 0) {
                    int hd = cq >> 3;
                    P.as_[(size_t)(n0 + n) * 4 + hd] = ps;
                    P.ad_[(size_t)(n0 + n) * 4 + hd] = pd;
                }
            }
            __syncthreads();
        }
    }
    grid.sync();

    // ================= P1: bucket histogram =================
    {
        int* hist = (int*)smem;
        for (int i = t; i < nB; i += 256) hist[i] = 0;
        __syncthreads();
        int chunk = (E + g - 1) / g;
        int lo = bid * chunk, hi = lo + chunk; if (hi > E) hi = E;
        for (int e = lo + t; e < hi; e += 256) atomicAdd(&hist[P.ei[E + e] >> 8], 1);
        __syncthreads();
        for (int i = t; i < nB; i += 256) { int c = hist[i]; if (c) atomicAdd(&P.bSize[i], c); }
    }
    grid.sync();

    // ================= P2: bucket scan (block 0, 2 buckets/thread) =================
    if (bid == 0) {
        int* part = (int*)smem;
        int c0 = t * 2;
        int v0 = (c0 < nB) ? P.bSize[c0] : 0;
        int v1 = (c0 + 1 < nB) ? P.bSize[c0 + 1] : 0;
        part[t] = v0 + v1;
        __syncthreads();
        for (int off = 1; off < 256; off <<= 1) {
            int u = (t >= off) ? part[t - off] : 0;
            __syncthreads();
            part[t] += u;
            __syncthreads();
        }
        int ex = (t == 0) ? 0 : part[t - 1];
        if (c0 < nB)     { P.bOff[c0] = ex;      P.bCur[c0] = ex; }
        if (c0 + 1 < nB) { P.bOff[c0 + 1] = ex + v0; P.bCur[c0 + 1] = ex + v0; }
        if (t == 255) P.bOff[nB] = part[255];
    }
    grid.sync();

    // ================= P3: partition into buckets =================
    {
        int* hist = (int*)smem;           // 2KB
        int* base = (int*)(smem + 2048);  // 2KB
        int chunk = (E + g - 1) / g;
        int lo = bid * chunk, hi = lo + chunk; if (hi > E) hi = E;
        for (int i = t; i < nB; i += 256) hist[i] = 0;
        __syncthreads();
        for (int e = lo + t; e < hi; e += 256) atomicAdd(&hist[P.ei[E + e] >> 8], 1);
        __syncthreads();
        for (int i = t; i < nB; i += 256) {
            int c = hist[i];
            base[i] = c ? atomicAdd(&P.bCur[i], c) : 0;
            hist[i] = 0;
        }
        __syncthreads();
        for (int e = lo + t; e < hi; e += 256) {
            int s = P.ei[e], d = P.ei[E + e];
            int b = d >> 8;
            int pos = base[b] + atomicAdd(&hist[b], 1);
            P.bucketBuf[pos] = ((unsigned)(d & 255) << 24) | (unsigned)s;
        }
    }
    grid.sync();

    // ================= P4: build rowPtr + sSrc per bucket =================
    {
        int* lhist = (int*)smem;          // 1KB
        int* sOut  = (int*)(smem + 1024); // 32KB
        for (int b = bid; b < nB; b += g) {
            int dlo = b << 8;
            int dhi = dlo + 256; if (dhi > N) dhi = N;
            int base = P.bOff[b], end = P.bOff[b + 1];
            int sz = end - base;
            lhist[t] = 0;
            __syncthreads();
            for (int i = t; i < sz; i += 256) atomicAdd(&lhist[P.bucketBuf[base + i] >> 24], 1);
            __syncthreads();
            for (int off = 1; off < 256; off <<= 1) {
                int u = (t >= off) ? lhist[t - off] : 0;
                __syncthreads();
                lhist[t] += u;
                __syncthreads();
            }
            int pfx = (t == 0) ? 0 : lhist[t - 1];
            if (dlo + t < dhi) P.rowPtr[dlo + t] = base + pfx;
            if (t == 0 && dhi == N) P.rowPtr[N] = end;
            __syncthreads();
            lhist[t] = pfx;
            __syncthreads();
            if (sz <= 8192) {
                for (int i = t; i < sz; i += 256) {
                    unsigned int p = P.bucketBuf[base + i];
                    int pos = atomicAdd(&lhist[p >> 24], 1);
                    sOut[pos] = (int)(p & 0xffffffu);
                }
                __syncthreads();
                for (int i = t; i < sz; i += 256) P.sSrc[base + i] = sOut[i];
            } else {
                for (int i = t; i < sz; i += 256) {
                    unsigned int p = P.bucketBuf[base + i];
                    int pos = atomicAdd(&lhist[p >> 24], 1);
                    P.sSrc[base + pos] = (int)(p & 0xffffffu);
                }
            }
            __syncthreads();
        }
    }
    grid.sync();

    // ================= agg macro (used twice) =================
#define AGG_PHASE(HSRC, ODST)                                                          \
    {                                                                                  \
        const int l = t & 15;                                                          \
        const int hd = l >> 2;                                                         \
        const uint4* h4 = (const uint4*)(HSRC);                                        \
        for (int d0 = bid * 16; d0 < N; d0 += g * 16) {                                \
            int d = d0 + (t >> 4);                                                     \
            if (d < N) {                                                               \
                int b0 = P.rowPtr[d], b1 = P.rowPtr[d + 1];                            \
                float4 adv = ((const float4*)P.ad_)[d];                                \
                float4 sm = make_float4(0.f, 0.f, 0.f, 0.f);                           \
                for (int j = b0 + l; j < b1; j += 16) {                                \
                    int s = P.sSrc[j];                                                 \
                    float4 a = ((const float4*)P.as_)[s];                              \
                    sm.x += __expf(lrelu(a.x + adv.x));                                \
                    sm.y += __expf(lrelu(a.y + adv.y));                                \
                    sm.z += __expf(lrelu(a.z + adv.z));                                \
                    sm.w += __expf(lrelu(a.w + adv.w));                                \
                }                                                                      \
                for (int off = 1; off < 16; off <<= 1) {                               \
                    sm.x += __shfl_xor(sm.x, off);                                     \
                    sm.y += __shfl_xor(sm.y, off);                                     \
                    sm.z += __shfl_xor(sm.z, off);                                     \
                    sm.w += __shfl_xor(sm.w, off);                                     \
                }                                                                      \
                float sumh = (hd == 0) ? sm.x : (hd == 1) ? sm.y : (hd == 2) ? sm.z : sm.w; \
                float advh = (hd == 0) ? adv.x : (hd == 1) ? adv.y : (hd == 2) ? adv.z : adv.w; \
                float inv = 1.f / (sumh + 1e-16f);                                     \
                float4 acc0 = make_float4(0.f, 0.f, 0.f, 0.f);                         \
                float4 acc1 = make_float4(0.f, 0.f, 0.f, 0.f);                         \
                int j = b0;                                                            \
                for (; j + 4 <= b1; j += 4) {                                          \
                    int s0 = P.sSrc[j], s1 = P.sSrc[j + 1], s2 = P.sSrc[j + 2], s3 = P.sSrc[j + 3]; \
                    float w0 = __expf(lrelu(P.as_[(size_t)s0 * 4 + hd] + advh));       \
                    float w1 = __expf(lrelu(P.as_[(size_t)s1 * 4 + hd] + advh));       \
                    float w2 = __expf(lrelu(P.as_[(size_t)s2 * 4 + hd] + advh));       \
                    float w3 = __expf(lrelu(P.as_[(size_t)s3 * 4 + hd] + advh));       \
                    uint4 u0 = h4[(size_t)s0 * 16 + l];                                \
                    uint4 u1 = h4[(size_t)s1 * 16 + l];                                \
                    uint4 u2 = h4[(size_t)s2 * 16 + l];                                \
                    uint4 u3 = h4[(size_t)s3 * 16 + l];                                \
                    acc0.x = fmaf(w0, bflo(u0.x), acc0.x); acc0.y = fmaf(w0, bfhi(u0.x), acc0.y); \
                    acc0.z = fmaf(w0, bflo(u0.y), acc0.z); acc0.w = fmaf(w0, bfhi(u0.y), acc0.w); \
                    acc1.x = fmaf(w0, bflo(u0.z), acc1.x); acc1.y = fmaf(w0, bfhi(u0.z), acc1.y); \
                    acc1.z = fmaf(w0, bflo(u0.w), acc1.z); acc1.w = fmaf(w0, bfhi(u0.w), acc1.w); \
                    acc0.x = fmaf(w1, bflo(u1.x), acc0.x); acc0.y = fmaf(w1, bfhi(u1.x), acc0.y); \
                    acc0.z = fmaf(w1, bflo(u1.y), acc0.z); acc0.w = fmaf(w1, bfhi(u1.y), acc0.w); \
                    acc1.x = fmaf(w1, bflo(u1.z), acc1.x); acc1.y = fmaf(w1, bfhi(u1.z), acc1.y); \
                    acc1.z = fmaf(w1, bflo(u1.w), acc1.z); acc1.w = fmaf(w1, bfhi(u1.w), acc1.w); \
                    acc0.x = fmaf(w2, bflo(u2.x), acc0.x); acc0.y = fmaf(w2, bfhi(u2.x), acc0.y); \
                    acc0.z = fmaf(w2, bflo(u2.y), acc0.z); acc0.w = fmaf(w2, bfhi(u2.y), acc0.w); \
                    acc1.x = fmaf(w2, bflo(u2.z), acc1.x); acc1.y = fmaf(w2, bfhi(u2.z), acc1.y); \
                    acc1.z = fmaf(w2, bflo(u2.w), acc1.z); acc1.w = fmaf(w2, bfhi(u2.w), acc1.w); \
                    acc0.x = fmaf(w3, bflo(u3.x), acc0.x); acc0.y = fmaf(w3, bfhi(u3.x), acc0.y); \
                    acc0.z = fmaf(w3, bflo(u3.y), acc0.z); acc0.w = fmaf(w3, bfhi(u3.y), acc0.w); \
                    acc1.x = fmaf(w3, bflo(u3.z), acc1.x); acc1.y = fmaf(w3, bfhi(u3.z), acc1.y); \
                    acc1.z = fmaf(w3, bflo(u3.w), acc1.z); acc1.w = fmaf(w3, bfhi(u3.w), acc1.w); \
                }                                                                      \
                for (; j < b1; ++j) {                                                  \
                    int s = P.sSrc[j];                                                 \
                    float w = __expf(lrelu(P.as_[(size_t)s * 4 + hd] + advh));         \
                    uint4 u = h4[(size_t)s * 16 + l];                                  \
                    acc0.x = fmaf(w, bflo(u.x), acc0.x); acc0.y = fmaf(w, bfhi(u.x), acc0.y); \
                    acc0.z = fmaf(w, bflo(u.y), acc0.z); acc0.w = fmaf(w, bfhi(u.y), acc0.w); \
                    acc1.x = fmaf(w, bflo(u.z), acc1.x); acc1.y = fmaf(w, bfhi(u.z), acc1.y); \
                    acc1.z = fmaf(w, bflo(u.w), acc1.z); acc1.w = fmaf(w, bfhi(u.w), acc1.w); \
                }                                                                      \
                acc0.x *= inv; acc0.y *= inv; acc0.z *= inv; acc0.w *= inv;            \
                acc1.x *= inv; acc1.y *= inv; acc1.z *= inv; acc1.w *= inv;            \
                ((uint4*)(ODST))[(size_t)d * 16 + l] = make_uint4(                     \
                    packbf(acc0.x, acc0.y), packbf(acc0.z, acc0.w),                    \
                    packbf(acc1.x, acc1.y), packbf(acc1.z, acc1.w));                   \
            }                                                                          \
        }                                                                              \
    }

    // ================= bnstats macro =================
#define BNSTATS_PHASE(SRC, SUMS)                                                       \
    {                                                                                  \
        float4* r1 = (float4*)smem;                                                    \
        float4* r2 = (float4*)(smem + 4096);                                           \
        int lane = t & 31, rg = t >> 5;                                                \
        const uint2* x2 = (const uint2*)(SRC);                                         \
        float4 s1 = make_float4(0.f, 0.f, 0.f, 0.f);                                   \
        float4 s2 = make_float4(0.f, 0.f, 0.f, 0.f);                                   \
        for (int n = bid * 8 + rg; n < N; n += g * 8) {                                \
            uint2 u = x2[(size_t)n * 32 + lane];                                       \
            float a = bflo(u.x), b = bfhi(u.x), c = bflo(u.y), e = bfhi(u.y);          \
            s1.x += a; s1.y += b; s1.z += c; s1.w += e;                                \
            s2.x += a * a; s2.y += b * b; s2.z += c * c; s2.w += e * e;                \
        }                                                                              \
        r1[t] = s1; r2[t] = s2;                                                        \
        __syncthreads();                                                               \
        if (t < 32) {                                                                  \
            float4 a = r1[t], b = r2[t];                                               \
            for (int k = 1; k < 8; ++k) {                                              \
                float4 c = r1[t + 32 * k], e = r2[t + 32 * k];                         \
                a.x += c.x; a.y += c.y; a.z += c.z; a.w += c.w;                        \
                b.x += e.x; b.y += e.y; b.z += e.z; b.w += e.w;                        \
            }                                                                          \
            atomicAdd(&(SUMS)[t * 4 + 0], (double)a.x);                                \
            atomicAdd(&(SUMS)[t * 4 + 1], (double)a.y);                                \
            atomicAdd(&(SUMS)[t * 4 + 2], (double)a.z);                                \
            atomicAdd(&(SUMS)[t * 4 + 3], (double)a.w);                                \
            atomicAdd(&(SUMS)[128 + t * 4 + 0], (double)b.x);                          \
            atomicAdd(&(SUMS)[128 + t * 4 + 1], (double)b.y);                          \
            atomicAdd(&(SUMS)[128 + t * 4 + 2], (double)b.z);                          \
            atomicAdd(&(SUMS)[128 + t * 4 + 3], (double)b.w);                          \
        }                                                                              \
        __syncthreads();                                                               \
    }

    // ================= P5: agg layer 1 =================
    AGG_PHASE(P.hbuf, P.outb)
    grid.sync();

    // ================= P6: bnstats layer 1 =================
    BNSTATS_PHASE(P.outb, P.bnsumA)
    grid.sync();

    // ================= P7: gemm2 (BN1 fold, bf16 in, bf16 h out) =================
    {
        float* xs   = (float*)smem;            // 32KB
        float* sc_s = (float*)(smem + 32768);  // 512B
        float* sh_s = (float*)(smem + 33280);  // 512B
        if (t < 128) {
            double mu = P.bnsumA[t] / (double)N;
            double var = P.bnsumA[128 + t] / (double)N - mu * mu;
            if (var < 0.0) var = 0.0;
            double rs = 1.0 / sqrt(var + 1e-5);
            float sc = (float)((double)P.bng1[t] * rs);
            sc_s[t] = sc;
            sh_s[t] = P.bnb1[t] - (float)mu * sc;
        }
        __syncthreads();
        const float4* W4 = (const float4*)P.W2;
        float4 atS = ((const float4*)P.attS2)[cq];
        float4 atD = ((const float4*)P.attD2)[cq];
        const uint2* x2 = (const uint2*)P.outb;
        for (int n0 = bid * 64; n0 < N; n0 += g * 64) {
            int nrem = N - n0; if (nrem > 64) nrem = 64;
            for (int idx = t; idx < 64 * 32; idx += 256) {
                int n = idx >> 5, k8 = idx & 31;
                float4 v = make_float4(0.f, 0.f, 0.f, 0.f);
                if (n < nrem) {
                    uint2 u = x2[(size_t)(n0 + n) * 32 + k8];
                    float4 sc = ((const float4*)sc_s)[k8];
                    float4 sh = ((const float4*)sh_s)[k8];
                    v.x = fmaf(bflo(u.x), sc.x, sh.x); v.x = v.x > 0.f ? v.x : 0.f;
                    v.y = fmaf(bfhi(u.x), sc.y, sh.y); v.y = v.y > 0.f ? v.y : 0.f;
                    v.z = fmaf(bflo(u.y), sc.z, sh.z); v.z = v.z > 0.f ? v.z : 0.f;
                    v.w = fmaf(bfhi(u.y), sc.w, sh.w); v.w = v.w > 0.f ? v.w : 0.f;
                }
                *(float4*)(xs + n * 128 + k8 * 4) = v;
            }
            __syncthreads();
            float4 acc[8];
#pragma unroll
            for (int j = 0; j < 8; ++j) acc[j] = make_float4(0.f, 0.f, 0.f, 0.f);
#pragma unroll 2
            for (int k4 = 0; k4 < 32; ++k4) {
                float4 w0 = W4[(k4 * 4 + 0) * 32 + cq];
                float4 w1 = W4[(k4 * 4 + 1) * 32 + cq];
                float4 w2 = W4[(k4 * 4 + 2) * 32 + cq];
                float4 w3 = W4[(k4 * 4 + 3) * 32 + cq];
#pragma unroll
                for (int j = 0; j < 8; ++j) {
                    float4 xv = *(const float4*)(xs + (nr * 8 + j) * 128 + k4 * 4);
                    acc[j].x = fmaf(xv.x, w0.x, acc[j].x); acc[j].y = fmaf(xv.x, w0.y, acc[j].y);
                    acc[j].z = fmaf(xv.x, w0.z, acc[j].z); acc[j].w = fmaf(xv.x, w0.w, acc[j].w);
                    acc[j].x = fmaf(xv.y, w1.x, acc[j].x); acc[j].y = fmaf(xv.y, w1.y, acc[j].y);
                    acc[j].z = fmaf(xv.y, w1.z, acc[j].z); acc[j].w = fmaf(xv.y, w1.w, acc[j].w);
                    acc[j].x = fmaf(xv.z, w2.x, acc[j].x); acc[j].y = fmaf(xv.z, w2.y, acc[j].y);
                    acc[j].z = fmaf(xv.z, w2.z, acc[j].z); acc[j].w = fmaf(xv.z, w2.w, acc[j].w);
                    acc[j].x = fmaf(xv.w, w3.x, acc[j].x); acc[j].y = fmaf(xv.w, w3.y, acc[j].y);
                    acc[j].z = fmaf(xv.w, w3.z, acc[j].z); acc[j].w = fmaf(xv.w, w3.w, acc[j].w);
                }
            }
#pragma unroll
            for (int j = 0; j < 8; ++j) {
                int n = nr * 8 + j;
                bool ok = (n < nrem);
                if (ok) {
                    ((uint2*)(P.hbuf + (size_t)(n0 + n) * 128))[cq] =
                        make_uint2(packbf(acc[j].x, acc[j].y), packbf(acc[j].z, acc[j].w));
                }
                float ps = acc[j].x * atS.x + acc[j].y * atS.y + acc[j].z * atS.z + acc[j].w * atS.w;
                float pd = acc[j].x * atD.x + acc[j].y * atD.y + acc[j].z * atD.z + acc[j].w * atD.w;
                ps += __shfl_xor(ps, 1); pd += __shfl_xor(pd, 1);
                ps += __shfl_xor(ps, 2); pd += __shfl_xor(pd, 2);
                ps += __shfl_xor(ps, 4); pd += __shfl_xor(pd, 4);
                if (ok && (cq & 7) == 0) {
                    int hd = cq >> 3;
                    P.as_[(size_t)(n0 + n) * 4 + hd] = ps;
                    P.ad_[(size_t)(n0 + n) * 4 + hd] = pd;
                }
            }
            __syncthreads();
        }
    }
    grid.sync();

    // ================= P8: agg layer 2 =================
    AGG_PHASE(P.hbuf, P.outb)
    grid.sync();

    // ================= P9: bnstats layer 2 =================
    BNSTATS_PHASE(P.outb, P.bnsumB)
    grid.sync();

    // ================= P10: pool (BN2 fold) =================
    {
        float* sc_s = (float*)smem;          // 512B
        float* sh_s = (float*)(smem + 512);  // 512B
        if (t < 128) {
            double mu = P.bnsumB[t] / (double)N;
            double var = P.bnsumB[128 + t] / (double)N - mu * mu;
            if (var < 0.0) var = 0.0;
            double rs = 1.0 / sqrt(var + 1e-5);
            float sc = (float)((double)P.bng2[t] * rs);
            sc_s[t] = sc;
            sh_s[t] = P.bnb2[t] - (float)mu * sc;
        }
        __syncthreads();
        int lane = t & 31;
        int r = t >> 5;
        float4 sc = ((const float4*)sc_s)[lane];
        float4 sh = ((const float4*)sh_s)[lane];
        const uint2* x2 = (const uint2*)P.outb;
        for (int n0 = bid * 64; n0 < N; n0 += g * 64) {
            int n1 = n0 + 64; if (n1 > N) n1 = N;
            float4 acc = make_float4(0.f, 0.f, 0.f, 0.f);
            int cnt = 0, cur = -1;
            for (int n = n0 + r; n < n1; n += 8) {
                int gb = (int)P.batch[n];
                if (gb != cur) {
                    if (cur >= 0) {
                        atomicAdd(&P.gsum[cur * 128 + lane * 4 + 0], acc.x);
                        atomicAdd(&P.gsum[cur * 128 + lane * 4 + 1], acc.y);
                        atomicAdd(&P.gsum[cur * 128 + lane * 4 + 2], acc.z);
                        atomicAdd(&P.gsum[cur * 128 + lane * 4 + 3], acc.w);
                        if (lane == 0) atomicAdd(&P.gcnt[cur], (float)cnt);
                    }
                    acc = make_float4(0.f, 0.f, 0.f, 0.f); cnt = 0; cur = gb;
                }
                uint2 u = x2[(size_t)n * 32 + lane];
                float4 v = make_float4(bflo(u.x), bfhi(u.x), bflo(u.y), bfhi(u.y));
                v.x = fmaf(v.x, sc.x, sh.x); v.x = v.x > 0.f ? v.x : 0.f;
                v.y = fmaf(v.y, sc.y, sh.y); v.y = v.y > 0.f ? v.y : 0.f;
                v.z = fmaf(v.z, sc.z, sh.z); v.z = v.z > 0.f ? v.z : 0.f;
                v.w = fmaf(v.w, sc.w, sh.w); v.w = v.w > 0.f ? v.w : 0.f;
                acc.x += v.x; acc.y += v.y; acc.z += v.z; acc.w += v.w;
                cnt++;
            }
            if (cur >= 0) {
                atomicAdd(&P.gsum[cur * 128 + lane * 4 + 0], acc.x);
                atomicAdd(&P.gsum[cur * 128 + lane * 4 + 1], acc.y);
                atomicAdd(&P.gsum[cur * 128 + lane * 4 + 2], acc.z);
                atomicAdd(&P.gsum[cur * 128 + lane * 4 + 3], acc.w);
                if (lane == 0) atomicAdd(&P.gcnt[cur], (float)cnt);
            }
        }
    }
    grid.sync();

    // ================= P11: dense head (block 0) =================
    if (bid == 0) {
        float* Y1 = (float*)smem;            // 16KB
        float* Y2 = (float*)(smem + 16384);  // 8KB
        for (int i = t; i < 64 * 128; i += 256) {
            int gg = i >> 7;
            float cv = P.gcnt[gg]; if (cv < 1.f) cv = 1.f;
            P.gmean[i] = P.gsum[i] / cv;
        }
        __syncthreads();
        for (int i = t; i < 64 * 64; i += 256) {
            int r = i >> 6, j = i & 63;
            float a = 0.f;
            for (int k = 0; k < 128; ++k) a = fmaf(P.gmean[r * 128 + k], P.d1W[k * 64 + j], a);
            Y1[i] = a + P.d1b[j];
        }
        __syncthreads();
        if (t < 64) {
            float s1 = 0.f, s2 = 0.f;
            for (int r = 0; r < 64; ++r) { float v = Y1[r * 64 + t]; s1 += v; s2 += v * v; }
            float mu = s1 / 64.f, var = s2 / 64.f - mu * mu; if (var < 0.f) var = 0.f;
            float rs = 1.0f / sqrtf(var + 1e-5f);
            float scv = P.gd1[t] * rs, shv = P.bd1[t] - mu * scv;
            for (int r = 0; r < 64; ++r) {
                float v = fmaf(Y1[r * 64 + t], scv, shv);
                Y1[r * 64 + t] = v > 0.f ? v : 0.f;
            }
        }
        __syncthreads();
        for (int i = t; i < 64 * 32; i += 256) {
            int r = i >> 5, j = i & 31;
            float a = 0.f;
            for (int k = 0; k < 64; ++k) a = fmaf(Y1[r * 64 + k], P.d2W[k * 32 + j], a);
            Y2[i] = a + P.d2b[j];
        }
        __syncthreads();
        if (t < 32) {
            float s1 = 0.f, s2 = 0.f;
            for (int r = 0; r < 64; ++r) { float v = Y2[r * 32 + t]; s1 += v; s2 += v * v; }
            float mu = s1 / 64.f, var = s2 / 64.f - mu * mu; if (var < 0.f) var = 0.f;
            float rs = 1.0f / sqrtf(var + 1e-5f);
            float scv = P.gd2[t] * rs, shv = P.bd2[t] - mu * scv;
            for (int r = 0; r < 64; ++r) {
                float v = fmaf(Y2[r * 32 + t], scv, shv);
                Y2[r * 32 + t] = v > 0.f ? v : 0.f;
            }
        }
        __syncthreads();
        {
            int r = t >> 2, j = t & 3;
            float a = 0.f;
            for (int k = 0; k < 32; ++k) a = fmaf(Y2[r * 32 + k], P.fcW[k * 4 + j], a);
            P.out[t] = a + P.fcb[j];
        }
    }
#undef AGG_PHASE
#undef BNSTATS_PHASE
}

extern "C" void kernel_launch(void* const* d_in, const int* in_sizes, int n_in,
                              void* d_out, int out_size, void* d_ws, size_t ws_size,
                              hipStream_t stream) {
    const int N = in_sizes[0] / 16;
    const int E = in_sizes[1] / 2;
    const int nB = (N + 255) >> 8;

    MegaP P;
    P.x      = (const float*)d_in[0];
    P.ei     = (const int*)d_in[1];
    P.batch  = (const int*)d_in[2];
    P.W1     = (const float*)d_in[3];
    P.attS1  = (const float*)d_in[5];
    P.attD1  = (const float*)d_in[6];
    P.bng1   = (const float*)d_in[7];
    P.bnb1   = (const float*)d_in[8];
    P.W2     = (const float*)d_in[9];
    P.attS2  = (const float*)d_in[11];
    P.attD2  = (const float*)d_in[12];
    P.bng2   = (const float*)d_in[13];
    P.bnb2   = (const float*)d_in[14];
    P.d1W    = (const float*)d_in[15];
    P.d1b    = (const float*)d_in[16];
    P.gd1    = (const float*)d_in[17];
    P.bd1    = (const float*)d_in[18];
    P.d2W    = (const float*)d_in[19];
    P.d2b    = (const float*)d_in[20];
    P.gd2    = (const float*)d_in[21];
    P.bd2    = (const float*)d_in[22];
    P.fcW    = (const float*)d_in[23];
    P.fcb    = (const float*)d_in[24];
    P.out    = (float*)d_out;

    float* ws = (float*)d_ws;
    size_t o = 0;
    P.hbuf = (unsigned short*)(ws + o); o += (size_t)N * 64;
    P.outb = (unsigned short*)(ws + o); o += (size_t)N * 64;
    P.as_  = ws + o; o += (size_t)N * 4;
    P.ad_  = ws + o; o += (size_t)N * 4;
    size_t zoff = o;
    P.bnsumA = (double*)(ws + o); o += 512;
    P.bnsumB = (double*)(ws + o); o += 512;
    P.gsum   = ws + o; o += 64 * 128;
    P.gcnt   = ws + o; o += 64;
    P.bSize  = (int*)(ws + o); o += 1024;
    P.zbase  = ws + zoff;
    P.zcount = (int)(o - zoff);
    P.rowPtr = (int*)(ws + o); o += (size_t)N + 1;
    P.sSrc   = (int*)(ws + o); o += E;
    P.bOff   = (int*)(ws + o); o += 1025;
    P.bCur   = (int*)(ws + o); o += 1024;
    P.bucketBuf = (unsigned int*)(ws + o); o += E;
    P.gmean  = ws + o; o += 64 * 128;
    P.N = N; P.E = E; P.nB = nB;

    int dev = 0;
    hipGetDevice(&dev);
    int cus = 0;
    hipDeviceGetAttribute(&cus, hipDeviceAttributeMultiprocessorCount, dev);
    if (cus <= 0) cus = 256;
    int maxB = 0;
    hipOccupancyMaxActiveBlocksPerMultiprocessor(&maxB, k_mega, 256, 0);
    if (maxB < 1) maxB = 1;
    int grid = maxB * cus;
    if (grid > 2048) grid = 2048;

    void* args[] = { &P };
    hipLaunchCooperativeKernel((void*)k_mega, dim3(grid), dim3(256), args, 0, stream);
}